// Round 1
// baseline (235.318 us; speedup 1.0000x reference)
//
#include <hip/hip_runtime.h>

#define BSZ 512
#define DIM 768
#define NTYPES 16
#define MARGIN 1.0

// ---------------------------------------------------------------------------
// Kernel 1: pairwise L2 distance matrix. One block per row (anchor) a.
// Row e_a staged in LDS; each thread computes 2 columns with float4 loads.
// Block 0 also zero-inits the double accumulator (ws is poisoned 0xAA).
// ---------------------------------------------------------------------------
__global__ void dist_kernel(const float* __restrict__ emb,
                            float* __restrict__ dist,
                            double* __restrict__ accum) {
    const int a = blockIdx.x;
    __shared__ float sA[DIM];
    for (int k = threadIdx.x; k < DIM; k += blockDim.x) sA[k] = emb[a * DIM + k];
    if (a == 0 && threadIdx.x == 0) *accum = 0.0;
    __syncthreads();

    for (int j = threadIdx.x; j < BSZ; j += blockDim.x) {
        const float* ej = emb + j * DIM;
        float acc = 0.f;
        #pragma unroll 4
        for (int k = 0; k < DIM; k += 4) {
            float4 va = *(const float4*)(sA + k);
            float4 vb = *(const float4*)(ej + k);
            float d0 = va.x - vb.x;
            float d1 = va.y - vb.y;
            float d2 = va.z - vb.z;
            float d3 = va.w - vb.w;
            acc += d0 * d0 + d1 * d1 + d2 * d2 + d3 * d3;
        }
        dist[a * BSZ + j] = sqrtf(acc);
    }
}

// ---------------------------------------------------------------------------
// Kernel 2: per-anchor triplet sum. One block per anchor a.
// Brute-force over all (p, n) pairs; validity = (t[p]==t[a]) && (t[n]!=t[a]).
// Distance row + types live in LDS. drow[n] access is 2-way bank aliased
// (free on gfx950); drow[p]/stypes[p] are wave-uniform broadcasts.
// ---------------------------------------------------------------------------
__global__ void triplet_kernel(const float* __restrict__ dist,
                               const int* __restrict__ types,
                               double* __restrict__ accum) {
    const int a = blockIdx.x;
    __shared__ float drow[BSZ];
    __shared__ int stypes[BSZ];
    __shared__ float wsum[4];

    for (int j = threadIdx.x; j < BSZ; j += blockDim.x) {
        drow[j] = dist[a * BSZ + j];
        stypes[j] = types[j];
    }
    __syncthreads();

    const int ta = stypes[a];

    float local = 0.f;
    // idx = p*BSZ + n over all BSZ*BSZ pairs
    for (int idx = threadIdx.x; idx < BSZ * BSZ; idx += blockDim.x) {
        const int p = idx >> 9;        // idx / 512
        const int n = idx & (BSZ - 1); // idx % 512
        const bool valid = (stypes[p] == ta) & (stypes[n] != ta);
        const float v = drow[p] - drow[n] + (float)MARGIN;
        local += valid ? fmaxf(v, 0.f) : 0.f;
    }

    // wave64 shuffle reduce
    #pragma unroll
    for (int off = 32; off > 0; off >>= 1) local += __shfl_down(local, off);
    const int wave = threadIdx.x >> 6;
    const int lane = threadIdx.x & 63;
    if (lane == 0) wsum[wave] = local;
    __syncthreads();
    if (threadIdx.x == 0) {
        double s = (double)wsum[0] + (double)wsum[1] + (double)wsum[2] + (double)wsum[3];
        atomicAdd(accum, s);
    }
}

// ---------------------------------------------------------------------------
// Kernel 3: finalize. Count types -> exact integer V = sum_t c_t^2 (B - c_t).
// loss = (accum + (B^3 - V) * margin) / V   (invalid triplets each clamp to
// margin because the reference adds margin to ALL entries before the clamp).
// ---------------------------------------------------------------------------
__global__ void finalize_kernel(const int* __restrict__ types,
                                const double* __restrict__ accum,
                                float* __restrict__ out) {
    __shared__ int cnt[NTYPES];
    if (threadIdx.x < NTYPES) cnt[threadIdx.x] = 0;
    __syncthreads();
    for (int i = threadIdx.x; i < BSZ; i += blockDim.x) atomicAdd(&cnt[types[i]], 1);
    __syncthreads();
    if (threadIdx.x == 0) {
        long long V = 0;
        for (int t = 0; t < NTYPES; t++) {
            long long c = cnt[t];
            V += c * c * (long long)(BSZ - c);
        }
        const long long B3 = (long long)BSZ * BSZ * BSZ;
        double total = *accum + (double)(B3 - V) * MARGIN;
        out[0] = (float)(total / (double)V);
    }
}

extern "C" void kernel_launch(void* const* d_in, const int* in_sizes, int n_in,
                              void* d_out, int out_size, void* d_ws, size_t ws_size,
                              hipStream_t stream) {
    const int* types = (const int*)d_in[0];
    const float* emb = (const float*)d_in[1];
    float* out = (float*)d_out;

    float* dist = (float*)d_ws;
    double* accum = (double*)((char*)d_ws + (size_t)BSZ * BSZ * sizeof(float));

    dist_kernel<<<BSZ, 256, 0, stream>>>(emb, dist, accum);
    triplet_kernel<<<BSZ, 256, 0, stream>>>(dist, types, accum);
    finalize_kernel<<<1, 256, 0, stream>>>(types, accum, out);
}

// Round 2
// 92.695 us; speedup vs baseline: 2.5386x; 2.5386x over previous
//
#include <hip/hip_runtime.h>

#define BSZ 512
#define DIM 768
#define KT 32
#define NTYPES 16
#define MARGIN 1.0f

// ---------------------------------------------------------------------------
// Kernel 1: pairwise L2 distance, LDS-tiled.
// 32x32 output tile per block (grid 16x16 = 256 blocks), 16x16 threads,
// 2x2 register micro-tile per thread. K staged in chunks of 32, stored
// transposed s[k][i] with pad 34 (float2-aligned, conflict-free reads,
// 2-way-aliased writes = free). Next chunk's float4 prefetched into regs
// across the compute loop to hide global latency at 4 waves/CU.
// Direct (a-b)^2 accumulation: exact, no norms pass, no max(,0) needed.
// ---------------------------------------------------------------------------
__global__ __launch_bounds__(256) void dist_tiled(const float* __restrict__ emb,
                                                  float* __restrict__ dist,
                                                  double* __restrict__ accum) {
    const int tx = threadIdx.x, ty = threadIdx.y;   // 16 x 16
    const int t = ty * 16 + tx;
    const int i0 = blockIdx.y * 32, j0 = blockIdx.x * 32;
    if (blockIdx.x == 0 && blockIdx.y == 0 && t == 0) *accum = 0.0;

    __shared__ float sAT[KT][34];
    __shared__ float sBT[KT][34];

    const int li = t >> 3;   // 0..31  (row within tile)
    const int kg = t & 7;    // 0..7   (16B group within chunk)
    const float* gA = emb + (size_t)(i0 + li) * DIM + 4 * kg;
    const float* gB = emb + (size_t)(j0 + li) * DIM + 4 * kg;

    float4 pa = *(const float4*)gA;
    float4 pb = *(const float4*)gB;

    float a00 = 0.f, a01 = 0.f, a10 = 0.f, a11 = 0.f;

    const int NCH = DIM / KT;  // 24
    for (int c = 0; c < NCH; ++c) {
        __syncthreads();
        sAT[4 * kg + 0][li] = pa.x; sAT[4 * kg + 1][li] = pa.y;
        sAT[4 * kg + 2][li] = pa.z; sAT[4 * kg + 3][li] = pa.w;
        sBT[4 * kg + 0][li] = pb.x; sBT[4 * kg + 1][li] = pb.y;
        sBT[4 * kg + 2][li] = pb.z; sBT[4 * kg + 3][li] = pb.w;
        __syncthreads();
        if (c + 1 < NCH) {
            pa = *(const float4*)(gA + (c + 1) * KT);
            pb = *(const float4*)(gB + (c + 1) * KT);
        }
        #pragma unroll
        for (int k = 0; k < KT; ++k) {
            float2 av = *(const float2*)&sAT[k][2 * ty];
            float2 bv = *(const float2*)&sBT[k][2 * tx];
            float d;
            d = av.x - bv.x; a00 += d * d;
            d = av.x - bv.y; a01 += d * d;
            d = av.y - bv.x; a10 += d * d;
            d = av.y - bv.y; a11 += d * d;
        }
    }
    const int r0 = i0 + 2 * ty, c0 = j0 + 2 * tx;
    float2 o0 = make_float2(sqrtf(a00), sqrtf(a01));
    float2 o1 = make_float2(sqrtf(a10), sqrtf(a11));
    *(float2*)&dist[(size_t)r0 * BSZ + c0] = o0;
    *(float2*)&dist[(size_t)(r0 + 1) * BSZ + c0] = o1;
}

// ---------------------------------------------------------------------------
// Kernel 2: per-anchor triplet sum with pos/neg compaction.
// Ballot-based LDS compaction (2 LDS atomics per wave), then scan only the
// |P| x |N| (~32 x 480) real pairs: positive distance broadcast, negatives
// read stride-1 from LDS (2-way bank alias = free). 17x less work than the
// masked brute-force scan.
// ---------------------------------------------------------------------------
__global__ __launch_bounds__(256) void triplet_kernel(const float* __restrict__ dist,
                                                      const int* __restrict__ types,
                                                      double* __restrict__ accum) {
    const int a = blockIdx.x;
    const int tid = threadIdx.x;
    const int lane = tid & 63;
    __shared__ float pos[BSZ];
    __shared__ float neg[BSZ];
    __shared__ int npos, nneg;
    __shared__ float wsum[4];
    if (tid == 0) { npos = 0; nneg = 0; }
    const int ta = types[a];
    __syncthreads();

    for (int j = tid; j < BSZ; j += 256) {   // all 64 lanes active each iter
        const float d = dist[(size_t)a * BSZ + j];
        const bool isp = (types[j] == ta);
        const unsigned long long m = __ballot(isp);
        const unsigned long long below = m & ((1ull << lane) - 1ull);
        const int cp = __popcll(m);
        int basep = 0, basen = 0;
        if (lane == 0) {
            basep = atomicAdd(&npos, cp);
            basen = atomicAdd(&nneg, 64 - cp);
        }
        basep = __shfl(basep, 0);
        basen = __shfl(basen, 0);
        const int pbelow = (int)__popcll(below);
        if (isp) pos[basep + pbelow] = d;
        else     neg[basen + (lane - pbelow)] = d;
    }
    __syncthreads();
    const int np = npos, nn = nneg;

    float local = 0.f;
    for (int pi = 0; pi < np; ++pi) {
        const float dpm = pos[pi] + MARGIN;          // broadcast LDS read
        for (int n = tid; n < nn; n += 256)
            local += fmaxf(dpm - neg[n], 0.f);
    }

    #pragma unroll
    for (int off = 32; off > 0; off >>= 1) local += __shfl_down(local, off);
    if (lane == 0) wsum[tid >> 6] = local;
    __syncthreads();
    if (tid == 0) {
        double s = (double)wsum[0] + (double)wsum[1] + (double)wsum[2] + (double)wsum[3];
        atomicAdd(accum, s);
    }
}

// ---------------------------------------------------------------------------
// Kernel 3: finalize. Exact integer V = sum_t c_t^2 (B - c_t); each invalid
// triplet contributes exactly margin (reference adds margin pre-clamp).
// ---------------------------------------------------------------------------
__global__ void finalize_kernel(const int* __restrict__ types,
                                const double* __restrict__ accum,
                                float* __restrict__ out) {
    __shared__ int cnt[NTYPES];
    if (threadIdx.x < NTYPES) cnt[threadIdx.x] = 0;
    __syncthreads();
    for (int i = threadIdx.x; i < BSZ; i += blockDim.x) atomicAdd(&cnt[types[i]], 1);
    __syncthreads();
    if (threadIdx.x == 0) {
        long long V = 0;
        for (int t = 0; t < NTYPES; t++) {
            long long c = cnt[t];
            V += c * c * (long long)(BSZ - c);
        }
        const long long B3 = (long long)BSZ * BSZ * BSZ;
        double total = *accum + (double)(B3 - V) * (double)MARGIN;
        out[0] = (float)(total / (double)V);
    }
}

extern "C" void kernel_launch(void* const* d_in, const int* in_sizes, int n_in,
                              void* d_out, int out_size, void* d_ws, size_t ws_size,
                              hipStream_t stream) {
    const int* types = (const int*)d_in[0];
    const float* emb = (const float*)d_in[1];
    float* out = (float*)d_out;

    float* dist = (float*)d_ws;
    double* accum = (double*)((char*)d_ws + (size_t)BSZ * BSZ * sizeof(float));

    dist_tiled<<<dim3(16, 16), dim3(16, 16), 0, stream>>>(emb, dist, accum);
    triplet_kernel<<<BSZ, 256, 0, stream>>>(dist, types, accum);
    finalize_kernel<<<1, 256, 0, stream>>>(types, accum, out);
}

// Round 4
// 87.130 us; speedup vs baseline: 2.7008x; 1.0639x over previous
//
#include <hip/hip_runtime.h>

#define BSZ 512
#define DIM 768
#define KT 32
#define NCH (DIM / KT)   // 24
#define NTYPES 16
#define MARGIN 1.0f

// ---------------------------------------------------------------------------
// Kernel 1: pairwise L2 via na + nb - 2*dot (the reference's own formula).
// 32x32 tile / block (grid 16x16 = 256 = one per CU), 16x16 threads, 2x2
// micro-tile -> 4 FMA per k per thread (half the direct-form VALU cost).
// Double-buffered LDS (1 barrier/chunk): global float4 prefetch issued at
// loop top, written to buf[1-cur] while buf[cur] is being consumed.
// Norms fused into staging: each thread squares the float4s it already
// holds, 3-level shfl_xor reduces the 8 staging lanes per row. k-major
// transposed LDS layout, pad 34: A-reads broadcast (4 unique addrs), B-reads
// cover all 32 banks 2-way (free).
// ---------------------------------------------------------------------------
__global__ __launch_bounds__(256) void dist_tiled(const float* __restrict__ emb,
                                                  float* __restrict__ dist,
                                                  double* __restrict__ accum) {
    const int tx = threadIdx.x, ty = threadIdx.y;   // 16 x 16
    const int t = ty * 16 + tx;
    const int i0 = blockIdx.y * 32, j0 = blockIdx.x * 32;
    if (blockIdx.x == 0 && blockIdx.y == 0 && t == 0) *accum = 0.0;

    __shared__ float sA[2][KT][34];
    __shared__ float sB[2][KT][34];
    __shared__ float sNA[32], sNB[32];

    const int li = t >> 3;   // 0..31: row within tile
    const int kg = t & 7;    // 0..7 : 16B group within chunk
    const float* gA = emb + (size_t)(i0 + li) * DIM + 4 * kg;
    const float* gB = emb + (size_t)(j0 + li) * DIM + 4 * kg;

    // stage chunk 0 + start norm accumulation
    float4 pa = *(const float4*)gA;
    float4 pb = *(const float4*)gB;
    float na = pa.x * pa.x + pa.y * pa.y + pa.z * pa.z + pa.w * pa.w;
    float nb = pb.x * pb.x + pb.y * pb.y + pb.z * pb.z + pb.w * pb.w;
    sA[0][4 * kg + 0][li] = pa.x; sA[0][4 * kg + 1][li] = pa.y;
    sA[0][4 * kg + 2][li] = pa.z; sA[0][4 * kg + 3][li] = pa.w;
    sB[0][4 * kg + 0][li] = pb.x; sB[0][4 * kg + 1][li] = pb.y;
    sB[0][4 * kg + 2][li] = pb.z; sB[0][4 * kg + 3][li] = pb.w;
    __syncthreads();

    float a00 = 0.f, a01 = 0.f, a10 = 0.f, a11 = 0.f;

    for (int c = 0; c < NCH; ++c) {
        const int cur = c & 1;
        float4 qa, qb;
        if (c + 1 < NCH) {             // prefetch next chunk (in flight
            qa = *(const float4*)(gA + (c + 1) * KT);   //  across compute)
            qb = *(const float4*)(gB + (c + 1) * KT);
        }
        #pragma unroll
        for (int k = 0; k < KT; ++k) {
            float2 av = *(const float2*)&sA[cur][k][2 * ty];
            float2 bv = *(const float2*)&sB[cur][k][2 * tx];
            a00 = fmaf(av.x, bv.x, a00);
            a01 = fmaf(av.x, bv.y, a01);
            a10 = fmaf(av.y, bv.x, a10);
            a11 = fmaf(av.y, bv.y, a11);
        }
        if (c + 1 < NCH) {
            na += qa.x * qa.x + qa.y * qa.y + qa.z * qa.z + qa.w * qa.w;
            nb += qb.x * qb.x + qb.y * qb.y + qb.z * qb.z + qb.w * qb.w;
            const int nxt = 1 - cur;
            sA[nxt][4 * kg + 0][li] = qa.x; sA[nxt][4 * kg + 1][li] = qa.y;
            sA[nxt][4 * kg + 2][li] = qa.z; sA[nxt][4 * kg + 3][li] = qa.w;
            sB[nxt][4 * kg + 0][li] = qb.x; sB[nxt][4 * kg + 1][li] = qb.y;
            sB[nxt][4 * kg + 2][li] = qb.z; sB[nxt][4 * kg + 3][li] = qb.w;
        }
        __syncthreads();
    }

    // reduce norm partials across the 8 staging lanes of each row
    #pragma unroll
    for (int off = 1; off < 8; off <<= 1) {
        na += __shfl_xor(na, off);
        nb += __shfl_xor(nb, off);
    }
    if (kg == 0) { sNA[li] = na; sNB[li] = nb; }
    __syncthreads();

    const float nA0 = sNA[2 * ty], nA1 = sNA[2 * ty + 1];
    const float nB0 = sNB[2 * tx], nB1 = sNB[2 * tx + 1];
    float2 o0, o1;
    o0.x = sqrtf(fmaxf(nA0 + nB0 - 2.f * a00, 0.f));
    o0.y = sqrtf(fmaxf(nA0 + nB1 - 2.f * a01, 0.f));
    o1.x = sqrtf(fmaxf(nA1 + nB0 - 2.f * a10, 0.f));
    o1.y = sqrtf(fmaxf(nA1 + nB1 - 2.f * a11, 0.f));
    const int r0 = i0 + 2 * ty, c0 = j0 + 2 * tx;
    *(float2*)&dist[(size_t)r0 * BSZ + c0] = o0;
    *(float2*)&dist[(size_t)(r0 + 1) * BSZ + c0] = o1;
}

// ---------------------------------------------------------------------------
// Kernel 2: per-anchor triplet sum with pos/neg compaction (unchanged from
// R2 — measured fast). Ballot compaction, then scan only |P| x |N| pairs.
// ---------------------------------------------------------------------------
__global__ __launch_bounds__(256) void triplet_kernel(const float* __restrict__ dist,
                                                      const int* __restrict__ types,
                                                      double* __restrict__ accum) {
    const int a = blockIdx.x;
    const int tid = threadIdx.x;
    const int lane = tid & 63;
    __shared__ float pos[BSZ];
    __shared__ float neg[BSZ];
    __shared__ int npos, nneg;
    __shared__ float wsum[4];
    if (tid == 0) { npos = 0; nneg = 0; }
    const int ta = types[a];
    __syncthreads();

    for (int j = tid; j < BSZ; j += 256) {
        const float d = dist[(size_t)a * BSZ + j];
        const bool isp = (types[j] == ta);
        const unsigned long long m = __ballot(isp);
        const unsigned long long below = m & ((1ull << lane) - 1ull);
        const int cp = __popcll(m);
        int basep = 0, basen = 0;
        if (lane == 0) {
            basep = atomicAdd(&npos, cp);
            basen = atomicAdd(&nneg, 64 - cp);
        }
        basep = __shfl(basep, 0);
        basen = __shfl(basen, 0);
        const int pbelow = (int)__popcll(below);
        if (isp) pos[basep + pbelow] = d;
        else     neg[basen + (lane - pbelow)] = d;
    }
    __syncthreads();
    const int np = npos, nn = nneg;

    float local = 0.f;
    for (int pi = 0; pi < np; ++pi) {
        const float dpm = pos[pi] + MARGIN;          // broadcast LDS read
        for (int n = tid; n < nn; n += 256)
            local += fmaxf(dpm - neg[n], 0.f);
    }

    #pragma unroll
    for (int off = 32; off > 0; off >>= 1) local += __shfl_down(local, off);
    if (lane == 0) wsum[tid >> 6] = local;
    __syncthreads();
    if (tid == 0) {
        double s = (double)wsum[0] + (double)wsum[1] + (double)wsum[2] + (double)wsum[3];
        atomicAdd(accum, s);
    }
}

// ---------------------------------------------------------------------------
// Kernel 3: finalize. Exact integer V = sum_t c_t^2 (B - c_t); each invalid
// triplet contributes exactly margin (reference adds margin pre-clamp).
// ---------------------------------------------------------------------------
__global__ void finalize_kernel(const int* __restrict__ types,
                                const double* __restrict__ accum,
                                float* __restrict__ out) {
    __shared__ int cnt[NTYPES];
    if (threadIdx.x < NTYPES) cnt[threadIdx.x] = 0;
    __syncthreads();
    for (int i = threadIdx.x; i < BSZ; i += blockDim.x) atomicAdd(&cnt[types[i]], 1);
    __syncthreads();
    if (threadIdx.x == 0) {
        long long V = 0;
        for (int t = 0; t < NTYPES; t++) {
            long long c = cnt[t];
            V += c * c * (long long)(BSZ - c);
        }
        const long long B3 = (long long)BSZ * BSZ * BSZ;
        double total = *accum + (double)(B3 - V) * (double)MARGIN;
        out[0] = (float)(total / (double)V);
    }
}

extern "C" void kernel_launch(void* const* d_in, const int* in_sizes, int n_in,
                              void* d_out, int out_size, void* d_ws, size_t ws_size,
                              hipStream_t stream) {
    const int* types = (const int*)d_in[0];
    const float* emb = (const float*)d_in[1];
    float* out = (float*)d_out;

    float* dist = (float*)d_ws;
    double* accum = (double*)((char*)d_ws + (size_t)BSZ * BSZ * sizeof(float));

    dist_tiled<<<dim3(16, 16), dim3(16, 16), 0, stream>>>(emb, dist, accum);
    triplet_kernel<<<BSZ, 256, 0, stream>>>(dist, types, accum);
    finalize_kernel<<<1, 256, 0, stream>>>(types, accum, out);
}